// Round 3
// baseline (152968.701 us; speedup 1.0000x reference)
//
#include <hip/hip_runtime.h>
#include <cstdint>
#include <cstddef>
#include <math.h>

// Exact Viterbi decode: N=512 states, T=8192, M=50257 tokens.
// Forward recurrence is computed bit-exactly by ONE workgroup (the fp32
// rounding sequence at |v|~1e5 pins every argmax decision), with a provably
// exact two-pass row pruning: pass1 over L1 = {c_i >= M-DELTA}, whose column
// maxima give an achieved lower bound T = min_j lb_j; any row with
// c_i = fl(v_i+rowmax_i) < T is strictly below every column max (IEEE add is
// monotone), so pass2 only covers {c_i >= T} \ L1 (typically ~empty).

#define NT 512
#define TT 8192
#define MT 50257
#define DELTA1 3.0f

#define BT_L 32                  // backtrace segment length
#define BT_S (TT / BT_L)         // 256 segments

// ---- workspace layout (bytes) ----
#define WS_LOGPI   0u            // 512 f32
#define WS_VLAST   2048u         // 512 f32
#define WS_BOUND   4096u         // 257 i32
#define WS_ROWMAX  5632u         // 512 f32
#define WS_MAPS    8192u         // 256*512 u16 = 262144
#define WS_LA      270336u       // 512*512 f32 = 1048576 (row-major logA)
#define WS_EMIS    1318912u      // 8192*512 f32 = 16777216
#define WS_BP      18096128u     // 8192*512 u16 = 8388608
#define WS_NEED    26484736u

#define NEG_INF (-3.402823466e38f)

// Correctly-rounded fp32 logs via fp64 (verified: absmax 0 vs numpy ref).
__global__ void prep_logs(const float* __restrict__ A, const float* __restrict__ Pi,
                          float* __restrict__ lA, float* __restrict__ logPi) {
    int idx = blockIdx.x * blockDim.x + threadIdx.x;
    if (idx < NT * NT) {
        lA[idx] = (float)log((double)A[idx]);
    } else if (idx < NT * NT + NT) {
        int j = idx - NT * NT;
        logPi[j] = (float)log((double)Pi[j]);
    }
}

__global__ void prep_rowmax(const float* __restrict__ lA, float* __restrict__ rowmax) {
    __shared__ float s[4];
    int i = blockIdx.x;
    int t = threadIdx.x;                    // 256 threads
    float m = fmaxf(lA[i * NT + t], lA[i * NT + t + 256]);
    for (int k = 32; k >= 1; k >>= 1) m = fmaxf(m, __shfl_xor(m, k, 64));
    if ((t & 63) == 0) s[t >> 6] = m;
    __syncthreads();
    if (t == 0) {
        float r = fmaxf(fmaxf(s[0], s[1]), fmaxf(s[2], s[3]));
        rowmax[i] = r;                      // exact max of exact fp32 values
    }
}

__global__ void prep_emis(const float* __restrict__ B, const int* __restrict__ tok,
                          float* __restrict__ emis) {
    int idx = blockIdx.x * blockDim.x + threadIdx.x;   // t*512 + j
    if (idx >= TT * NT) return;
    int t = idx >> 9;
    int j = idx & (NT - 1);
    int tk = tok[t];
    float e;
    if (tk < 0) e = (float)log((double)(1.0f / 512.0f));
    else        e = (float)log((double)B[(size_t)j * MT + tk]);
    emis[idx] = e;
}

// Single-workgroup exact forward. 1024 threads: (h = tid>>9, j = tid&511).
// Thread (0,j) owns column j and carries v_j in a register; survivor values
// are shared only through compacted LDS arrays. 8 barriers/step.
__launch_bounds__(1024, 1)
__global__ void viterbi_fwd_exact(const float* __restrict__ lA,
                                  const float* __restrict__ rowmax,
                                  const float* __restrict__ emis,
                                  const float* __restrict__ logPi,
                                  unsigned short* __restrict__ bp,
                                  float* __restrict__ vlast) {
    __shared__ float vS[NT];        // pass1 survivor v values (compacted)
    __shared__ int   Sl[NT];        // pass1 survivor indices (ascending)
    __shared__ float vS2[NT];       // pass2 extras
    __shared__ int   Sl2[NT];
    __shared__ float pm[2][NT];     // h-partial max values
    __shared__ int   pb[2][NT];     // h-partial argmax indices
    __shared__ float redM[8];
    __shared__ int   redC[8];

    const int tid  = threadIdx.x;
    const int j    = tid & (NT - 1);
    const int h    = tid >> 9;
    const int lane = tid & 63;
    const int wave = tid >> 6;      // h==0 => waves 0..7

    const bool h0 = (h == 0);
    float v = 0.0f, rmax = 0.0f;
    if (h0) {
        v    = logPi[j] + emis[j];  // exact v0 (single-rounded add == ref)
        rmax = rowmax[j];
    }

    const float* __restrict__ lAj = lA + j;

    float c = 0.0f, e = 0.0f, M = 0.0f, T = 0.0f;
    bool pred1 = false;
    unsigned long long mk = 0ull, mk2 = 0ull;
    float m = 0.0f; int b = 0;

    for (int t = 1; t < TT; ++t) {
        // P1: c_i and its wave-max
        if (h0) {
            e = emis[(size_t)t * NT + j];          // prefetch, used in P9
            c = v + rmax;                          // fl(v_i + rowmax_i)
            float wm = c;
            for (int k = 32; k >= 1; k >>= 1) wm = fmaxf(wm, __shfl_xor(wm, k, 64));
            if (lane == 0) redM[wave] = wm;
        }
        __syncthreads();                            // B1

        // P2: M, L1 predicate, per-wave counts
        if (h0) {
            M = redM[0];
            #pragma unroll
            for (int w = 1; w < 8; ++w) M = fmaxf(M, redM[w]);
            pred1 = (c >= M - DELTA1);
            mk = __ballot(pred1);
            if (lane == 0) redC[wave] = __popcll(mk);
        }
        __syncthreads();                            // B2

        // P3: compact L1 (ascending i)
        int nL1 = 0;
        {
            #pragma unroll
            for (int w = 0; w < 8; ++w) nL1 += redC[w];
        }
        if (h0) {
            int pre = 0;
            for (int w = 0; w < wave; ++w) pre += redC[w];
            int pos = pre + __popcll(mk & ((1ull << lane) - 1ull));
            if (pred1) { Sl[pos] = j; vS[pos] = v; }
        }
        __syncthreads();                            // B3

        // P4: pass1 — exact max/argmax over L1 rows (both halves, interleaved)
        {
            float m1 = NEG_INF; int b1 = 0;
            #pragma unroll 4
            for (int s = h; s < nL1; s += 2) {
                int i0   = Sl[s];
                float vi = vS[s];
                float a  = lAj[(size_t)i0 * NT];    // coalesced, L2-resident
                float sc = vi + a;                  // single-rounded add == ref
                if (sc > m1) { m1 = sc; b1 = i0; }  // ascending i => first-index
            }
            pm[h][j] = m1; pb[h][j] = b1;
        }
        __syncthreads();                            // B4

        // P5: merge halves; lb_j = merged max; wave-min of lb
        if (h0) {
            float m0 = pm[0][j]; int b0 = pb[0][j];
            float m1 = pm[1][j]; int b1 = pb[1][j];
            if (m1 > m0 || (m1 == m0 && b1 < b0)) { m = m1; b = b1; }
            else                                  { m = m0; b = b0; }
            float mn = m;
            for (int k = 32; k >= 1; k >>= 1) mn = fminf(mn, __shfl_xor(mn, k, 64));
            if (lane == 0) redM[wave] = mn;
        }
        __syncthreads();                            // B5

        // P6: T = min_j lb_j; extras predicate
        if (h0) {
            T = redM[0];
            #pragma unroll
            for (int w = 1; w < 8; ++w) T = fminf(T, redM[w]);
            bool pred2 = (c >= T) && !pred1;        // >= keeps potential ties
            mk2 = __ballot(pred2);
            if (lane == 0) redC[wave] = __popcll(mk2);
        }
        __syncthreads();                            // B6

        // P7: compact extras
        int nEx = 0;
        {
            #pragma unroll
            for (int w = 0; w < 8; ++w) nEx += redC[w];
        }
        if (h0) {
            int pre = 0;
            for (int w = 0; w < wave; ++w) pre += redC[w];
            int pos = pre + __popcll(mk2 & ((1ull << lane) - 1ull));
            bool pred2 = (c >= T) && !pred1;
            if (pred2) { Sl2[pos] = j; vS2[pos] = v; }
        }
        __syncthreads();                            // B7

        // P8: pass2 over extras (usually ~0 rows)
        {
            float m2 = NEG_INF; int b2 = 0;
            #pragma unroll 4
            for (int s = h; s < nEx; s += 2) {
                int i0   = Sl2[s];
                float vi = vS2[s];
                float a  = lAj[(size_t)i0 * NT];
                float sc = vi + a;
                if (sc > m2) { m2 = sc; b2 = i0; }
            }
            pm[h][j] = m2; pb[h][j] = b2;
        }
        __syncthreads();                            // B8

        // P9: final merge (value desc, index asc — exact first-index argmax),
        //     then vn = fl(max + e) == reference.
        if (h0) {
            float x = pm[0][j]; int y = pb[0][j];
            if (x > m || (x == m && y < b)) { m = x; b = y; }
            x = pm[1][j]; y = pb[1][j];
            if (x > m || (x == m && y < b)) { m = x; b = y; }
            float vn = m + e;
            bp[(size_t)t * NT + j] = (unsigned short)b;
            v = vn;
            if (t == TT - 1) vlast[j] = vn;
        }
        // no barrier needed: v is private; all LDS hazards covered by B1..B3
    }
}

// ---- backtrace: per-segment map composition (verified exact) ----
__launch_bounds__(NT, 1)
__global__ void bt_maps(const unsigned short* __restrict__ bp,
                        unsigned short* __restrict__ maps) {
    __shared__ unsigned short bps[BT_L * NT];   // 32 KB
    const int s = blockIdx.x;
    const int tlo = BT_L * s + 1;
    int thi = BT_L * (s + 1); if (thi > TT - 1) thi = TT - 1;
    const int nt = thi - tlo + 1;
    for (int k = threadIdx.x; k < nt * NT; k += NT)
        bps[k] = bp[(size_t)tlo * NT + k];
    __syncthreads();
    int cur = threadIdx.x;                      // state at t = thi
    for (int r = nt - 1; r >= 0; --r) cur = bps[r * NT + cur];
    maps[s * NT + threadIdx.x] = (unsigned short)cur;  // state at t = 32*s
}

__launch_bounds__(NT, 1)
__global__ void bt_bound(const float* __restrict__ vlast,
                         const unsigned short* __restrict__ maps,
                         int* __restrict__ bound) {
    __shared__ float sv[NT];
    __shared__ int   si[NT];
    int j = threadIdx.x;
    sv[j] = vlast[j]; si[j] = j;
    __syncthreads();
    for (int off = NT / 2; off > 0; off >>= 1) {
        if (j < off) {
            float v2 = sv[j + off]; int i2 = si[j + off];
            if (v2 > sv[j] || (v2 == sv[j] && i2 < si[j])) { sv[j] = v2; si[j] = i2; }
        }
        __syncthreads();
    }
    if (j == 0) {
        int cur = si[0];
        bound[BT_S] = cur;                      // state at t = 8191
        for (int s = BT_S - 1; s >= 0; --s) {
            cur = maps[s * NT + cur];
            bound[s] = cur;                     // state at t = 32*s
        }
    }
}

__launch_bounds__(NT, 1)
__global__ void bt_path(const unsigned short* __restrict__ bp,
                        const int* __restrict__ bound,
                        int* __restrict__ path) {
    __shared__ unsigned short bps[BT_L * NT];
    const int s = blockIdx.x;
    const int tlo = BT_L * s + 1;
    int thi = BT_L * (s + 1); if (thi > TT - 1) thi = TT - 1;
    const int nt = thi - tlo + 1;
    for (int k = threadIdx.x; k < nt * NT; k += NT)
        bps[k] = bp[(size_t)tlo * NT + k];
    __syncthreads();
    if (threadIdx.x == 0) {
        int cur = bound[s + 1];
        if (s == BT_S - 1) path[TT - 1] = cur;
        for (int r = nt - 1; r >= 0; --r) {
            cur = bps[r * NT + cur];
            path[tlo - 1 + r] = cur;            // path[32s .. thi-1]
        }
    }
}

extern "C" void kernel_launch(void* const* d_in, const int* in_sizes, int n_in,
                              void* d_out, int out_size, void* d_ws, size_t ws_size,
                              hipStream_t stream) {
    const int*   tok = (const int*)d_in[0];
    const float* A   = (const float*)d_in[1];
    const float* B   = (const float*)d_in[2];
    const float* Pi  = (const float*)d_in[3];
    int* path = (int*)d_out;
    char* ws = (char*)d_ws;
    if (ws_size < (size_t)WS_NEED) return;

    float* logPi          = (float*)(ws + WS_LOGPI);
    float* vlast          = (float*)(ws + WS_VLAST);
    int*   bound          = (int*)(ws + WS_BOUND);
    float* rowmax         = (float*)(ws + WS_ROWMAX);
    unsigned short* maps  = (unsigned short*)(ws + WS_MAPS);
    float* lA             = (float*)(ws + WS_LA);
    float* emis           = (float*)(ws + WS_EMIS);
    unsigned short* bpp   = (unsigned short*)(ws + WS_BP);

    prep_logs  <<<(NT * NT + NT + 255) / 256, 256, 0, stream>>>(A, Pi, lA, logPi);
    prep_emis  <<<(TT * NT) / 256,            256, 0, stream>>>(B, tok, emis);
    prep_rowmax<<<NT, 256, 0, stream>>>(lA, rowmax);
    viterbi_fwd_exact<<<1, 1024, 0, stream>>>(lA, rowmax, emis, logPi, bpp, vlast);
    bt_maps  <<<BT_S, NT, 0, stream>>>(bpp, maps);
    bt_bound <<<1,    NT, 0, stream>>>(vlast, maps, bound);
    bt_path  <<<BT_S, NT, 0, stream>>>(bpp, bound, path);
}

// Round 4
// 115269.666 us; speedup vs baseline: 1.3271x; 1.3271x over previous
//
#include <hip/hip_runtime.h>
#include <cstdint>
#include <cstddef>
#include <math.h>

// Exact Viterbi decode: N=512 states, T=8192, M=50257 tokens.
// Forward recurrence computed bit-exactly by ONE workgroup (fp32 rounding at
// |v|~1e5 pins every argmax decision). Per step, an exactness-preserving
// two-pass pruning: pass1 over heuristic L1 = {v_i >= max v - DELTA}; its
// achieved column maxima give T = min_j lb_j; rows with fl(v_i+R) < T (R =
// global max row-max, IEEE add monotone) cannot win or tie any column.
// Pass2 (rare) covers {fl(v+R) >= T} \ L1. All tie-breaks are (value strict >,
// then smaller index-VALUE), so nondeterministic survivor-list order (LDS
// atomic allocation) cannot change results.

#define NT 512
#define TT 8192
#define MT 50257
#define DELTA1 0.14f
#define NEG_INF (-3.402823466e38f)

#define BT_L 32                  // backtrace segment length
#define BT_S (TT / BT_L)         // 256 segments

// ---- workspace layout (bytes) ----
#define WS_LOGPI   0u            // 512 f32
#define WS_VLAST   2048u         // 512 f32
#define WS_BOUND   4096u         // 257 i32
#define WS_ROWMAX  5632u         // 512 f32
#define WS_MAPS    8192u         // 256*512 u16 = 262144
#define WS_LA      270336u       // 512*512 f32 = 1048576 (row-major logA)
#define WS_EMIS    1318912u      // 8192*512 f32 = 16777216
#define WS_BP      18096128u     // 8192*512 u16 = 8388608
#define WS_NEED    26484736u

// Correctly-rounded fp32 logs via fp64 (verified: absmax 0 vs numpy ref).
__global__ void prep_logs(const float* __restrict__ A, const float* __restrict__ Pi,
                          float* __restrict__ lA, float* __restrict__ logPi) {
    int idx = blockIdx.x * blockDim.x + threadIdx.x;
    if (idx < NT * NT) {
        lA[idx] = (float)log((double)A[idx]);
    } else if (idx < NT * NT + NT) {
        int j = idx - NT * NT;
        logPi[j] = (float)log((double)Pi[j]);
    }
}

__global__ void prep_rowmax(const float* __restrict__ lA, float* __restrict__ rowmax) {
    __shared__ float s[4];
    int i = blockIdx.x;
    int t = threadIdx.x;                    // 256 threads
    float m = fmaxf(lA[i * NT + t], lA[i * NT + t + 256]);
    for (int k = 32; k >= 1; k >>= 1) m = fmaxf(m, __shfl_xor(m, k, 64));
    if ((t & 63) == 0) s[t >> 6] = m;
    __syncthreads();
    if (t == 0) {
        float r = fmaxf(fmaxf(s[0], s[1]), fmaxf(s[2], s[3]));
        rowmax[i] = r;
    }
}

__global__ void prep_emis(const float* __restrict__ B, const int* __restrict__ tok,
                          float* __restrict__ emis) {
    int idx = blockIdx.x * blockDim.x + threadIdx.x;   // t*512 + j
    if (idx >= TT * NT) return;
    int t = idx >> 9;
    int j = idx & (NT - 1);
    int tk = tok[t];
    float e;
    if (tk < 0) e = (float)log((double)(1.0f / 512.0f));
    else        e = (float)log((double)B[(size_t)j * MT + tk]);
    emis[idx] = e;
}

// 1024 threads. h0 = tid<512: thread j owns column j, carries v_j in register.
// Scan layout: group G = tid>>3 owns columns 4G..4G+3; sub u = tid&7 strides
// the survivor list. 4 barriers/step common path.
__launch_bounds__(1024, 1)
__global__ void viterbi_fwd_exact(const float* __restrict__ lA,
                                  const float* __restrict__ rowmax,
                                  const float* __restrict__ emis,
                                  const float* __restrict__ logPi,
                                  unsigned short* __restrict__ bp,
                                  float* __restrict__ vlast) {
    __shared__ float  ering[16 * NT];        // 32 KB emission ring, slot = t & 15
    __shared__ float2 SV[544];               // pass1 survivors (v, bitcast idx)
    __shared__ float2 SV2[544];              // pass2 extras
    __shared__ alignas(16) float lb[NT];     // pass1 merged column max
    __shared__ alignas(16) int   bb[NT];     // pass1 merged argmax
    __shared__ alignas(16) float lb2[NT];
    __shared__ alignas(16) int   bb2[NT];
    __shared__ alignas(16) float redM[8];    // per-h0-wave v-max partials
    __shared__ alignas(16) float redT[16];   // per-wave T partials
    __shared__ alignas(16) float redR[8];
    __shared__ int nCtr, nCtr2;

    const int tid  = threadIdx.x;
    const int j    = tid & (NT - 1);
    const int lane = tid & 63;
    const int wave = tid >> 6;               // 0..15
    const int u    = tid & 7;
    const int G    = tid >> 3;               // 0..127 (columns 4G..4G+3)
    const bool h0  = (tid < NT);
    const unsigned long long below = (1ull << lane) - 1ull;

    // ---- pre-loop: v0, first M partials, R ----
    if (tid == 0) { nCtr = 0; nCtr2 = 0; }
    float v = 0.0f;
    if (h0) {
        v = logPi[j] + emis[j];              // exact v0 (single-rounded == ref)
        float wm = v;
        #pragma unroll
        for (int d = 1; d <= 32; d <<= 1) wm = fmaxf(wm, __shfl_xor(wm, d, 64));
        if (lane == 0) redM[wave] = wm;
        float r = rowmax[j];
        #pragma unroll
        for (int d = 1; d <= 32; d <<= 1) r = fmaxf(r, __shfl_xor(r, d, 64));
        if (lane == 0) redR[wave] = r;
    }
    __syncthreads();
    float R = redR[0];
    #pragma unroll
    for (int w = 1; w < 8; ++w) R = fmaxf(R, redR[w]);

    const float4* __restrict__ apG = (const float4*)lA + G;   // row i at + i*128

    for (int t = 1; t < TT; ++t) {
        // ---------------- PH_A: L1 select + compact; h1: emis batch ----------
        float M = fmaxf(fmaxf(fmaxf(redM[0], redM[1]), fmaxf(redM[2], redM[3])),
                        fmaxf(fmaxf(redM[4], redM[5]), fmaxf(redM[6], redM[7])));
        bool pred1 = false;
        if (h0) {
            pred1 = (v >= M - DELTA1);
            unsigned long long mk = __ballot(pred1);
            int base = 0;
            if (lane == 0) base = atomicAdd(&nCtr, __popcll(mk));
            base = __shfl(base, 0, 64);
            if (pred1) SV[base + __popcll(mk & below)] = make_float2(v, __int_as_float(j));
        } else {
            if ((t & 15) == 1) {             // prefetch emis[t .. t+15] -> ring
                int jp  = tid - NT;          // 0..511, 16 floats each
                int k   = jp >> 5;           // step offset 0..15
                int col = (jp & 31) << 4;    // 16-float column chunk
                if (t + k < TT) {
                    int slot = (t + k) & 15;
                    const float4* src = (const float4*)&emis[(size_t)(t + k) * NT + col];
                    float4* dst = (float4*)&ering[slot * NT + col];
                    dst[0] = src[0]; dst[1] = src[1]; dst[2] = src[2]; dst[3] = src[3];
                }
            }
            if (tid == NT + 100) nCtr2 = 0;  // read last step PH_D; next atomic PH_C
        }
        __syncthreads();                     // B_A

        // ---------------- PH_B: guarded scan over SV[0..n) ----------------
        int n  = nCtr;
        int nR = (n + 31) & ~31;
        float m0 = NEG_INF, m1 = NEG_INF, m2 = NEG_INF, m3 = NEG_INF;
        int   b0 = 0, b1 = 0, b2 = 0, b3 = 0;
        for (int s = u; s < nR; s += 32) {
            int s1 = s + 8, s2 = s + 16, s3 = s + 24;
            float2 q0 = SV[s  < n ? s  : 0];
            float2 q1 = SV[s1 < n ? s1 : 0];
            float2 q2 = SV[s2 < n ? s2 : 0];
            float2 q3 = SV[s3 < n ? s3 : 0];
            float va0 = (s  < n) ? q0.x : NEG_INF; int ia0 = __float_as_int(q0.y);
            float va1 = (s1 < n) ? q1.x : NEG_INF; int ia1 = __float_as_int(q1.y);
            float va2 = (s2 < n) ? q2.x : NEG_INF; int ia2 = __float_as_int(q2.y);
            float va3 = (s3 < n) ? q3.x : NEG_INF; int ia3 = __float_as_int(q3.y);
            float4 a0 = apG[(size_t)ia0 * 128];
            float4 a1 = apG[(size_t)ia1 * 128];
            float4 a2 = apG[(size_t)ia2 * 128];
            float4 a3 = apG[(size_t)ia3 * 128];
            float sc;
            sc = va0 + a0.x; if (sc > m0 || (sc == m0 && ia0 < b0)) { m0 = sc; b0 = ia0; }
            sc = va0 + a0.y; if (sc > m1 || (sc == m1 && ia0 < b1)) { m1 = sc; b1 = ia0; }
            sc = va0 + a0.z; if (sc > m2 || (sc == m2 && ia0 < b2)) { m2 = sc; b2 = ia0; }
            sc = va0 + a0.w; if (sc > m3 || (sc == m3 && ia0 < b3)) { m3 = sc; b3 = ia0; }
            sc = va1 + a1.x; if (sc > m0 || (sc == m0 && ia1 < b0)) { m0 = sc; b0 = ia1; }
            sc = va1 + a1.y; if (sc > m1 || (sc == m1 && ia1 < b1)) { m1 = sc; b1 = ia1; }
            sc = va1 + a1.z; if (sc > m2 || (sc == m2 && ia1 < b2)) { m2 = sc; b2 = ia1; }
            sc = va1 + a1.w; if (sc > m3 || (sc == m3 && ia1 < b3)) { m3 = sc; b3 = ia1; }
            sc = va2 + a2.x; if (sc > m0 || (sc == m0 && ia2 < b0)) { m0 = sc; b0 = ia2; }
            sc = va2 + a2.y; if (sc > m1 || (sc == m1 && ia2 < b1)) { m1 = sc; b1 = ia2; }
            sc = va2 + a2.z; if (sc > m2 || (sc == m2 && ia2 < b2)) { m2 = sc; b2 = ia2; }
            sc = va2 + a2.w; if (sc > m3 || (sc == m3 && ia2 < b3)) { m3 = sc; b3 = ia2; }
            sc = va3 + a3.x; if (sc > m0 || (sc == m0 && ia3 < b0)) { m0 = sc; b0 = ia3; }
            sc = va3 + a3.y; if (sc > m1 || (sc == m1 && ia3 < b1)) { m1 = sc; b1 = ia3; }
            sc = va3 + a3.z; if (sc > m2 || (sc == m2 && ia3 < b2)) { m2 = sc; b2 = ia3; }
            sc = va3 + a3.w; if (sc > m3 || (sc == m3 && ia3 < b3)) { m3 = sc; b3 = ia3; }
        }
        // intra-wave merge over the 8 subs (butterfly; (max, smaller-index))
        #pragma unroll
        for (int d = 1; d <= 4; d <<= 1) {
            float mm; int bx;
            mm = __shfl_xor(m0, d, 64); bx = __shfl_xor(b0, d, 64);
            if (mm > m0 || (mm == m0 && bx < b0)) { m0 = mm; b0 = bx; }
            mm = __shfl_xor(m1, d, 64); bx = __shfl_xor(b1, d, 64);
            if (mm > m1 || (mm == m1 && bx < b1)) { m1 = mm; b1 = bx; }
            mm = __shfl_xor(m2, d, 64); bx = __shfl_xor(b2, d, 64);
            if (mm > m2 || (mm == m2 && bx < b2)) { m2 = mm; b2 = bx; }
            mm = __shfl_xor(m3, d, 64); bx = __shfl_xor(b3, d, 64);
            if (mm > m3 || (mm == m3 && bx < b3)) { m3 = mm; b3 = bx; }
        }
        if (u == 0) {
            ((float4*)lb)[G] = make_float4(m0, m1, m2, m3);
            ((int4*)bb)[G]   = make_int4(b0, b1, b2, b3);
        }
        float tmin = fminf(fminf(m0, m1), fminf(m2, m3));
        #pragma unroll
        for (int d = 8; d <= 32; d <<= 1) tmin = fminf(tmin, __shfl_xor(tmin, d, 64));
        if (lane == 0) redT[wave] = tmin;
        __syncthreads();                     // B_B

        // ---------------- PH_C: T + extras compact ----------------
        float T = redT[0];
        #pragma unroll
        for (int w = 1; w < 16; ++w) T = fminf(T, redT[w]);
        if (h0) {
            float c = v + R;                 // fl(v+R) >= fl(v+a_ij) for all j
            bool pred2 = (c >= T) && !pred1;
            unsigned long long mk2 = __ballot(pred2);
            int base2 = 0;
            if (lane == 0) base2 = atomicAdd(&nCtr2, __popcll(mk2));
            base2 = __shfl(base2, 0, 64);
            if (pred2) SV2[base2 + __popcll(mk2 & below)] = make_float2(v, __int_as_float(j));
        }
        if (tid == 700) nCtr = 0;            // read in PH_B; next atomic PH_A(t+1)
        __syncthreads();                     // B_C

        // ---------------- PH_D: finalize (+rare pass2) + next-M partials -----
        int nEx = nCtr2;
        if (nEx == 0) {
            if (h0) {
                float e  = ering[((t & 15) << 9) | j];
                float vn = lb[j] + e;        // single-rounded == ref
                bp[(size_t)t * NT + j] = (unsigned short)bb[j];
                v = vn;
                if (t == TT - 1) vlast[j] = vn;
                float wm = vn;
                #pragma unroll
                for (int d = 1; d <= 32; d <<= 1) wm = fmaxf(wm, __shfl_xor(wm, d, 64));
                if (lane == 0) redM[wave] = wm;
            }
        } else {
            int nR2 = (nEx + 31) & ~31;
            float n0 = NEG_INF, n1 = NEG_INF, n2 = NEG_INF, n3 = NEG_INF;
            int   c0 = 0, c1 = 0, c2 = 0, c3 = 0;
            for (int s = u; s < nR2; s += 32) {
                int s1 = s + 8, s2 = s + 16, s3 = s + 24;
                float2 q0 = SV2[s  < nEx ? s  : 0];
                float2 q1 = SV2[s1 < nEx ? s1 : 0];
                float2 q2 = SV2[s2 < nEx ? s2 : 0];
                float2 q3 = SV2[s3 < nEx ? s3 : 0];
                float va0 = (s  < nEx) ? q0.x : NEG_INF; int ia0 = __float_as_int(q0.y);
                float va1 = (s1 < nEx) ? q1.x : NEG_INF; int ia1 = __float_as_int(q1.y);
                float va2 = (s2 < nEx) ? q2.x : NEG_INF; int ia2 = __float_as_int(q2.y);
                float va3 = (s3 < nEx) ? q3.x : NEG_INF; int ia3 = __float_as_int(q3.y);
                float4 a0 = apG[(size_t)ia0 * 128];
                float4 a1 = apG[(size_t)ia1 * 128];
                float4 a2 = apG[(size_t)ia2 * 128];
                float4 a3 = apG[(size_t)ia3 * 128];
                float sc;
                sc = va0 + a0.x; if (sc > n0 || (sc == n0 && ia0 < c0)) { n0 = sc; c0 = ia0; }
                sc = va0 + a0.y; if (sc > n1 || (sc == n1 && ia0 < c1)) { n1 = sc; c1 = ia0; }
                sc = va0 + a0.z; if (sc > n2 || (sc == n2 && ia0 < c2)) { n2 = sc; c2 = ia0; }
                sc = va0 + a0.w; if (sc > n3 || (sc == n3 && ia0 < c3)) { n3 = sc; c3 = ia0; }
                sc = va1 + a1.x; if (sc > n0 || (sc == n0 && ia1 < c0)) { n0 = sc; c0 = ia1; }
                sc = va1 + a1.y; if (sc > n1 || (sc == n1 && ia1 < c1)) { n1 = sc; c1 = ia1; }
                sc = va1 + a1.z; if (sc > n2 || (sc == n2 && ia1 < c2)) { n2 = sc; c2 = ia1; }
                sc = va1 + a1.w; if (sc > n3 || (sc == n3 && ia1 < c3)) { n3 = sc; c3 = ia1; }
                sc = va2 + a2.x; if (sc > n0 || (sc == n0 && ia2 < c0)) { n0 = sc; c0 = ia2; }
                sc = va2 + a2.y; if (sc > n1 || (sc == n1 && ia2 < c1)) { n1 = sc; c1 = ia2; }
                sc = va2 + a2.z; if (sc > n2 || (sc == n2 && ia2 < c2)) { n2 = sc; c2 = ia2; }
                sc = va2 + a2.w; if (sc > n3 || (sc == n3 && ia2 < c3)) { n3 = sc; c3 = ia2; }
                sc = va3 + a3.x; if (sc > n0 || (sc == n0 && ia3 < c0)) { n0 = sc; c0 = ia3; }
                sc = va3 + a3.y; if (sc > n1 || (sc == n1 && ia3 < c1)) { n1 = sc; c1 = ia3; }
                sc = va3 + a3.z; if (sc > n2 || (sc == n2 && ia3 < c2)) { n2 = sc; c2 = ia3; }
                sc = va3 + a3.w; if (sc > n3 || (sc == n3 && ia3 < c3)) { n3 = sc; c3 = ia3; }
            }
            #pragma unroll
            for (int d = 1; d <= 4; d <<= 1) {
                float mm; int bx;
                mm = __shfl_xor(n0, d, 64); bx = __shfl_xor(c0, d, 64);
                if (mm > n0 || (mm == n0 && bx < c0)) { n0 = mm; c0 = bx; }
                mm = __shfl_xor(n1, d, 64); bx = __shfl_xor(c1, d, 64);
                if (mm > n1 || (mm == n1 && bx < c1)) { n1 = mm; c1 = bx; }
                mm = __shfl_xor(n2, d, 64); bx = __shfl_xor(c2, d, 64);
                if (mm > n2 || (mm == n2 && bx < c2)) { n2 = mm; c2 = bx; }
                mm = __shfl_xor(n3, d, 64); bx = __shfl_xor(c3, d, 64);
                if (mm > n3 || (mm == n3 && bx < c3)) { n3 = mm; c3 = bx; }
            }
            if (u == 0) {
                ((float4*)lb2)[G] = make_float4(n0, n1, n2, n3);
                ((int4*)bb2)[G]   = make_int4(c0, c1, c2, c3);
            }
            __syncthreads();                 // B_D1 (rare only; uniform branch)
            if (h0) {
                float mj = lb[j];  int bj = bb[j];
                float mx = lb2[j]; int bx = bb2[j];
                if (mx > mj || (mx == mj && bx < bj)) { mj = mx; bj = bx; }
                float e  = ering[((t & 15) << 9) | j];
                float vn = mj + e;
                bp[(size_t)t * NT + j] = (unsigned short)bj;
                v = vn;
                if (t == TT - 1) vlast[j] = vn;
                float wm = vn;
                #pragma unroll
                for (int d = 1; d <= 32; d <<= 1) wm = fmaxf(wm, __shfl_xor(wm, d, 64));
                if (lane == 0) redM[wave] = wm;
            }
        }
        __syncthreads();                     // B_D
    }
}

// ---- backtrace: per-segment map composition (verified exact) ----
__launch_bounds__(NT, 1)
__global__ void bt_maps(const unsigned short* __restrict__ bp,
                        unsigned short* __restrict__ maps) {
    __shared__ unsigned short bps[BT_L * NT];
    const int s = blockIdx.x;
    const int tlo = BT_L * s + 1;
    int thi = BT_L * (s + 1); if (thi > TT - 1) thi = TT - 1;
    const int nt = thi - tlo + 1;
    for (int k = threadIdx.x; k < nt * NT; k += NT)
        bps[k] = bp[(size_t)tlo * NT + k];
    __syncthreads();
    int cur = threadIdx.x;
    for (int r = nt - 1; r >= 0; --r) cur = bps[r * NT + cur];
    maps[s * NT + threadIdx.x] = (unsigned short)cur;
}

__launch_bounds__(NT, 1)
__global__ void bt_bound(const float* __restrict__ vlast,
                         const unsigned short* __restrict__ maps,
                         int* __restrict__ bound) {
    __shared__ float sv[NT];
    __shared__ int   si[NT];
    int j = threadIdx.x;
    sv[j] = vlast[j]; si[j] = j;
    __syncthreads();
    for (int off = NT / 2; off > 0; off >>= 1) {
        if (j < off) {
            float v2 = sv[j + off]; int i2 = si[j + off];
            if (v2 > sv[j] || (v2 == sv[j] && i2 < si[j])) { sv[j] = v2; si[j] = i2; }
        }
        __syncthreads();
    }
    if (j == 0) {
        int cur = si[0];
        bound[BT_S] = cur;
        for (int s = BT_S - 1; s >= 0; --s) {
            cur = maps[s * NT + cur];
            bound[s] = cur;
        }
    }
}

__launch_bounds__(NT, 1)
__global__ void bt_path(const unsigned short* __restrict__ bp,
                        const int* __restrict__ bound,
                        int* __restrict__ path) {
    __shared__ unsigned short bps[BT_L * NT];
    const int s = blockIdx.x;
    const int tlo = BT_L * s + 1;
    int thi = BT_L * (s + 1); if (thi > TT - 1) thi = TT - 1;
    const int nt = thi - tlo + 1;
    for (int k = threadIdx.x; k < nt * NT; k += NT)
        bps[k] = bp[(size_t)tlo * NT + k];
    __syncthreads();
    if (threadIdx.x == 0) {
        int cur = bound[s + 1];
        if (s == BT_S - 1) path[TT - 1] = cur;
        for (int r = nt - 1; r >= 0; --r) {
            cur = bps[r * NT + cur];
            path[tlo - 1 + r] = cur;
        }
    }
}

extern "C" void kernel_launch(void* const* d_in, const int* in_sizes, int n_in,
                              void* d_out, int out_size, void* d_ws, size_t ws_size,
                              hipStream_t stream) {
    const int*   tok = (const int*)d_in[0];
    const float* A   = (const float*)d_in[1];
    const float* B   = (const float*)d_in[2];
    const float* Pi  = (const float*)d_in[3];
    int* path = (int*)d_out;
    char* ws = (char*)d_ws;
    if (ws_size < (size_t)WS_NEED) return;

    float* logPi          = (float*)(ws + WS_LOGPI);
    float* vlast          = (float*)(ws + WS_VLAST);
    int*   bound          = (int*)(ws + WS_BOUND);
    float* rowmax         = (float*)(ws + WS_ROWMAX);
    unsigned short* maps  = (unsigned short*)(ws + WS_MAPS);
    float* lA             = (float*)(ws + WS_LA);
    float* emis           = (float*)(ws + WS_EMIS);
    unsigned short* bpp   = (unsigned short*)(ws + WS_BP);

    prep_logs  <<<(NT * NT + NT + 255) / 256, 256, 0, stream>>>(A, Pi, lA, logPi);
    prep_emis  <<<(TT * NT) / 256,            256, 0, stream>>>(B, tok, emis);
    prep_rowmax<<<NT, 256, 0, stream>>>(lA, rowmax);
    viterbi_fwd_exact<<<1, 1024, 0, stream>>>(lA, rowmax, emis, logPi, bpp, vlast);
    bt_maps  <<<BT_S, NT, 0, stream>>>(bpp, maps);
    bt_bound <<<1,    NT, 0, stream>>>(vlast, maps, bound);
    bt_path  <<<BT_S, NT, 0, stream>>>(bpp, bound, path);
}

// Round 5
// 111871.582 us; speedup vs baseline: 1.3674x; 1.0304x over previous
//
#include <hip/hip_runtime.h>
#include <cstdint>
#include <cstddef>
#include <math.h>

// Exact Viterbi decode: N=512 states, T=8192, M=50257 tokens.
// Forward recurrence computed bit-exactly by ONE workgroup (fp32 rounding at
// |v|~1e5 pins every argmax decision). Per step, an exactness-preserving
// two-pass pruning: pass1 over heuristic L1 = {v_i >= max v - DELTA}; its
// achieved column maxima give T = min_j lb_j; rows with fl(v_i+R) < T (R =
// global max row-max, IEEE add monotone) cannot win or tie any column.
// Pass2 (rare) covers {fl(v+R) >= T} \ L1. All tie-breaks are (value strict >,
// then smaller index-VALUE), so nondeterministic survivor-list order (LDS
// atomic allocation) cannot change results.
//
// ROUND 5: blocks 1..255 are low-IPC "heater" blocks (dependent-FMA spin,
// agent-scope exit flag) to pin SCLK up — R2/R3/R4 all measured ~17.5 us/step
// against a ~2 us critical-path model, invariant to structure => suspected
// DPM down-clock with 1 busy CU.

#define NT 512
#define TT 8192
#define MT 50257
#define DELTA1 0.14f
#define NEG_INF (-3.402823466e38f)

#define BT_L 32                  // backtrace segment length
#define BT_S (TT / BT_L)         // 256 segments

// ---- workspace layout (bytes) ----
#define WS_LOGPI   0u            // 512 f32
#define WS_VLAST   2048u         // 512 f32
#define WS_BOUND   4096u         // 257 i32
#define WS_FLAG    5376u         // 1 u32 (heater exit flag)
#define WS_ROWMAX  5632u         // 512 f32
#define WS_MAPS    8192u         // 256*512 u16 = 262144
#define WS_LA      270336u       // 512*512 f32 = 1048576 (row-major logA)
#define WS_EMIS    1318912u      // 8192*512 f32 = 16777216
#define WS_BP      18096128u     // 8192*512 u16 = 8388608
#define WS_NEED    26484736u

// Correctly-rounded fp32 logs via fp64 (verified: absmax 0 vs numpy ref).
__global__ void prep_logs(const float* __restrict__ A, const float* __restrict__ Pi,
                          float* __restrict__ lA, float* __restrict__ logPi,
                          unsigned int* __restrict__ flag) {
    int idx = blockIdx.x * blockDim.x + threadIdx.x;
    if (idx < NT * NT) {
        lA[idx] = (float)log((double)A[idx]);
    } else if (idx < NT * NT + NT) {
        int j = idx - NT * NT;
        logPi[j] = (float)log((double)Pi[j]);
    } else if (idx == NT * NT + NT) {
        *flag = 0u;                          // cleared before every fwd launch
    }
}

__global__ void prep_rowmax(const float* __restrict__ lA, float* __restrict__ rowmax) {
    __shared__ float s[4];
    int i = blockIdx.x;
    int t = threadIdx.x;                    // 256 threads
    float m = fmaxf(lA[i * NT + t], lA[i * NT + t + 256]);
    for (int k = 32; k >= 1; k >>= 1) m = fmaxf(m, __shfl_xor(m, k, 64));
    if ((t & 63) == 0) s[t >> 6] = m;
    __syncthreads();
    if (t == 0) {
        float r = fmaxf(fmaxf(s[0], s[1]), fmaxf(s[2], s[3]));
        rowmax[i] = r;
    }
}

__global__ void prep_emis(const float* __restrict__ B, const int* __restrict__ tok,
                          float* __restrict__ emis) {
    int idx = blockIdx.x * blockDim.x + threadIdx.x;   // t*512 + j
    if (idx >= TT * NT) return;
    int t = idx >> 9;
    int j = idx & (NT - 1);
    int tk = tok[t];
    float e;
    if (tk < 0) e = (float)log((double)(1.0f / 512.0f));
    else        e = (float)log((double)B[(size_t)j * MT + tk]);
    emis[idx] = e;
}

// 1024 threads. Block 0: h0 = tid<512: thread j owns column j, carries v_j in
// register. Scan layout: group G = tid>>3 owns columns 4G..4G+3; sub u = tid&7
// strides the survivor list. 4 barriers/step common path.
// Blocks 1..255: heater spin (tid<256 only; no barriers).
__launch_bounds__(1024, 1)
__global__ void viterbi_fwd_exact(const float* __restrict__ lA,
                                  const float* __restrict__ rowmax,
                                  const float* __restrict__ emis,
                                  const float* __restrict__ logPi,
                                  unsigned short* __restrict__ bp,
                                  float* __restrict__ vlast,
                                  unsigned int* __restrict__ flag) {
    __shared__ float  ering[16 * NT];        // 32 KB emission ring, slot = t & 15
    __shared__ float2 SV[544];               // pass1 survivors (v, bitcast idx)
    __shared__ float2 SV2[544];              // pass2 extras
    __shared__ alignas(16) float lb[NT];     // pass1 merged column max
    __shared__ alignas(16) int   bb[NT];     // pass1 merged argmax
    __shared__ alignas(16) float lb2[NT];
    __shared__ alignas(16) int   bb2[NT];
    __shared__ alignas(16) float redM[8];    // per-h0-wave v-max partials
    __shared__ alignas(16) float redT[16];   // per-wave T partials
    __shared__ alignas(16) float redR[8];
    __shared__ int nCtr, nCtr2;

    if (blockIdx.x != 0) {
        // ---- heater: keep SCLK boosted; low issue pressure (dependent FMA) ----
        if (threadIdx.x < 256) {
            float x = 1.0f + (float)threadIdx.x * 1e-5f;
            while (__hip_atomic_load(flag, __ATOMIC_RELAXED,
                                     __HIP_MEMORY_SCOPE_AGENT) == 0u) {
                #pragma unroll 16
                for (int k = 0; k < 128; ++k)
                    x = __builtin_fmaf(x, 0.99999988f, 1.1920929e-7f);
                ering[threadIdx.x] = x;      // LDS side effect: loop not elidable
            }
        }
        return;
    }

    const int tid  = threadIdx.x;
    const int j    = tid & (NT - 1);
    const int lane = tid & 63;
    const int wave = tid >> 6;               // 0..15
    const int u    = tid & 7;
    const int G    = tid >> 3;               // 0..127 (columns 4G..4G+3)
    const bool h0  = (tid < NT);
    const unsigned long long below = (1ull << lane) - 1ull;

    // ---- pre-loop: v0, first M partials, R ----
    if (tid == 0) { nCtr = 0; nCtr2 = 0; }
    float v = 0.0f;
    if (h0) {
        v = logPi[j] + emis[j];              // exact v0 (single-rounded == ref)
        float wm = v;
        #pragma unroll
        for (int d = 1; d <= 32; d <<= 1) wm = fmaxf(wm, __shfl_xor(wm, d, 64));
        if (lane == 0) redM[wave] = wm;
        float r = rowmax[j];
        #pragma unroll
        for (int d = 1; d <= 32; d <<= 1) r = fmaxf(r, __shfl_xor(r, d, 64));
        if (lane == 0) redR[wave] = r;
    }
    __syncthreads();
    float R = redR[0];
    #pragma unroll
    for (int w = 1; w < 8; ++w) R = fmaxf(R, redR[w]);

    const float4* __restrict__ apG = (const float4*)lA + G;   // row i at + i*128

    for (int t = 1; t < TT; ++t) {
        // ---------------- PH_A: L1 select + compact; h1: emis batch ----------
        float M = fmaxf(fmaxf(fmaxf(redM[0], redM[1]), fmaxf(redM[2], redM[3])),
                        fmaxf(fmaxf(redM[4], redM[5]), fmaxf(redM[6], redM[7])));
        bool pred1 = false;
        if (h0) {
            pred1 = (v >= M - DELTA1);
            unsigned long long mk = __ballot(pred1);
            int base = 0;
            if (lane == 0) base = atomicAdd(&nCtr, __popcll(mk));
            base = __shfl(base, 0, 64);
            if (pred1) SV[base + __popcll(mk & below)] = make_float2(v, __int_as_float(j));
        } else {
            if ((t & 15) == 1) {             // prefetch emis[t .. t+15] -> ring
                int jp  = tid - NT;          // 0..511, 16 floats each
                int k   = jp >> 5;           // step offset 0..15
                int col = (jp & 31) << 4;    // 16-float column chunk
                if (t + k < TT) {
                    int slot = (t + k) & 15;
                    const float4* src = (const float4*)&emis[(size_t)(t + k) * NT + col];
                    float4* dst = (float4*)&ering[slot * NT + col];
                    dst[0] = src[0]; dst[1] = src[1]; dst[2] = src[2]; dst[3] = src[3];
                }
            }
            if (tid == NT + 100) nCtr2 = 0;  // read last step PH_D; next atomic PH_C
        }
        __syncthreads();                     // B_A

        // ---------------- PH_B: guarded scan over SV[0..n) ----------------
        int n  = nCtr;
        int nR = (n + 31) & ~31;
        float m0 = NEG_INF, m1 = NEG_INF, m2 = NEG_INF, m3 = NEG_INF;
        int   b0 = 0, b1 = 0, b2 = 0, b3 = 0;
        for (int s = u; s < nR; s += 32) {
            int s1 = s + 8, s2 = s + 16, s3 = s + 24;
            float2 q0 = SV[s  < n ? s  : 0];
            float2 q1 = SV[s1 < n ? s1 : 0];
            float2 q2 = SV[s2 < n ? s2 : 0];
            float2 q3 = SV[s3 < n ? s3 : 0];
            float va0 = (s  < n) ? q0.x : NEG_INF; int ia0 = __float_as_int(q0.y);
            float va1 = (s1 < n) ? q1.x : NEG_INF; int ia1 = __float_as_int(q1.y);
            float va2 = (s2 < n) ? q2.x : NEG_INF; int ia2 = __float_as_int(q2.y);
            float va3 = (s3 < n) ? q3.x : NEG_INF; int ia3 = __float_as_int(q3.y);
            float4 a0 = apG[(size_t)ia0 * 128];
            float4 a1 = apG[(size_t)ia1 * 128];
            float4 a2 = apG[(size_t)ia2 * 128];
            float4 a3 = apG[(size_t)ia3 * 128];
            float sc;
            sc = va0 + a0.x; if (sc > m0 || (sc == m0 && ia0 < b0)) { m0 = sc; b0 = ia0; }
            sc = va0 + a0.y; if (sc > m1 || (sc == m1 && ia0 < b1)) { m1 = sc; b1 = ia0; }
            sc = va0 + a0.z; if (sc > m2 || (sc == m2 && ia0 < b2)) { m2 = sc; b2 = ia0; }
            sc = va0 + a0.w; if (sc > m3 || (sc == m3 && ia0 < b3)) { m3 = sc; b3 = ia0; }
            sc = va1 + a1.x; if (sc > m0 || (sc == m0 && ia1 < b0)) { m0 = sc; b0 = ia1; }
            sc = va1 + a1.y; if (sc > m1 || (sc == m1 && ia1 < b1)) { m1 = sc; b1 = ia1; }
            sc = va1 + a1.z; if (sc > m2 || (sc == m2 && ia1 < b2)) { m2 = sc; b2 = ia1; }
            sc = va1 + a1.w; if (sc > m3 || (sc == m3 && ia1 < b3)) { m3 = sc; b3 = ia1; }
            sc = va2 + a2.x; if (sc > m0 || (sc == m0 && ia2 < b0)) { m0 = sc; b0 = ia2; }
            sc = va2 + a2.y; if (sc > m1 || (sc == m1 && ia2 < b1)) { m1 = sc; b1 = ia2; }
            sc = va2 + a2.z; if (sc > m2 || (sc == m2 && ia2 < b2)) { m2 = sc; b2 = ia2; }
            sc = va2 + a2.w; if (sc > m3 || (sc == m3 && ia2 < b3)) { m3 = sc; b3 = ia2; }
            sc = va3 + a3.x; if (sc > m0 || (sc == m0 && ia3 < b0)) { m0 = sc; b0 = ia3; }
            sc = va3 + a3.y; if (sc > m1 || (sc == m1 && ia3 < b1)) { m1 = sc; b1 = ia3; }
            sc = va3 + a3.z; if (sc > m2 || (sc == m2 && ia3 < b2)) { m2 = sc; b2 = ia3; }
            sc = va3 + a3.w; if (sc > m3 || (sc == m3 && ia3 < b3)) { m3 = sc; b3 = ia3; }
        }
        // intra-wave merge over the 8 subs (butterfly; (max, smaller-index))
        #pragma unroll
        for (int d = 1; d <= 4; d <<= 1) {
            float mm; int bx;
            mm = __shfl_xor(m0, d, 64); bx = __shfl_xor(b0, d, 64);
            if (mm > m0 || (mm == m0 && bx < b0)) { m0 = mm; b0 = bx; }
            mm = __shfl_xor(m1, d, 64); bx = __shfl_xor(b1, d, 64);
            if (mm > m1 || (mm == m1 && bx < b1)) { m1 = mm; b1 = bx; }
            mm = __shfl_xor(m2, d, 64); bx = __shfl_xor(b2, d, 64);
            if (mm > m2 || (mm == m2 && bx < b2)) { m2 = mm; b2 = bx; }
            mm = __shfl_xor(m3, d, 64); bx = __shfl_xor(b3, d, 64);
            if (mm > m3 || (mm == m3 && bx < b3)) { m3 = mm; b3 = bx; }
        }
        if (u == 0) {
            ((float4*)lb)[G] = make_float4(m0, m1, m2, m3);
            ((int4*)bb)[G]   = make_int4(b0, b1, b2, b3);
        }
        float tmin = fminf(fminf(m0, m1), fminf(m2, m3));
        #pragma unroll
        for (int d = 8; d <= 32; d <<= 1) tmin = fminf(tmin, __shfl_xor(tmin, d, 64));
        if (lane == 0) redT[wave] = tmin;
        __syncthreads();                     // B_B

        // ---------------- PH_C: T + extras compact ----------------
        float T = redT[0];
        #pragma unroll
        for (int w = 1; w < 16; ++w) T = fminf(T, redT[w]);
        if (h0) {
            float c = v + R;                 // fl(v+R) >= fl(v+a_ij) for all j
            bool pred2 = (c >= T) && !pred1;
            unsigned long long mk2 = __ballot(pred2);
            int base2 = 0;
            if (lane == 0) base2 = atomicAdd(&nCtr2, __popcll(mk2));
            base2 = __shfl(base2, 0, 64);
            if (pred2) SV2[base2 + __popcll(mk2 & below)] = make_float2(v, __int_as_float(j));
        }
        if (tid == 700) nCtr = 0;            // read in PH_B; next atomic PH_A(t+1)
        __syncthreads();                     // B_C

        // ---------------- PH_D: finalize (+rare pass2) + next-M partials -----
        int nEx = nCtr2;
        if (nEx == 0) {
            if (h0) {
                float e  = ering[((t & 15) << 9) | j];
                float vn = lb[j] + e;        // single-rounded == ref
                bp[(size_t)t * NT + j] = (unsigned short)bb[j];
                v = vn;
                if (t == TT - 1) vlast[j] = vn;
                float wm = vn;
                #pragma unroll
                for (int d = 1; d <= 32; d <<= 1) wm = fmaxf(wm, __shfl_xor(wm, d, 64));
                if (lane == 0) redM[wave] = wm;
            }
        } else {
            int nR2 = (nEx + 31) & ~31;
            float n0 = NEG_INF, n1 = NEG_INF, n2 = NEG_INF, n3 = NEG_INF;
            int   c0 = 0, c1 = 0, c2 = 0, c3 = 0;
            for (int s = u; s < nR2; s += 32) {
                int s1 = s + 8, s2 = s + 16, s3 = s + 24;
                float2 q0 = SV2[s  < nEx ? s  : 0];
                float2 q1 = SV2[s1 < nEx ? s1 : 0];
                float2 q2 = SV2[s2 < nEx ? s2 : 0];
                float2 q3 = SV2[s3 < nEx ? s3 : 0];
                float va0 = (s  < nEx) ? q0.x : NEG_INF; int ia0 = __float_as_int(q0.y);
                float va1 = (s1 < nEx) ? q1.x : NEG_INF; int ia1 = __float_as_int(q1.y);
                float va2 = (s2 < nEx) ? q2.x : NEG_INF; int ia2 = __float_as_int(q2.y);
                float va3 = (s3 < nEx) ? q3.x : NEG_INF; int ia3 = __float_as_int(q3.y);
                float4 a0 = apG[(size_t)ia0 * 128];
                float4 a1 = apG[(size_t)ia1 * 128];
                float4 a2 = apG[(size_t)ia2 * 128];
                float4 a3 = apG[(size_t)ia3 * 128];
                float sc;
                sc = va0 + a0.x; if (sc > n0 || (sc == n0 && ia0 < c0)) { n0 = sc; c0 = ia0; }
                sc = va0 + a0.y; if (sc > n1 || (sc == n1 && ia0 < c1)) { n1 = sc; c1 = ia0; }
                sc = va0 + a0.z; if (sc > n2 || (sc == n2 && ia0 < c2)) { n2 = sc; c2 = ia0; }
                sc = va0 + a0.w; if (sc > n3 || (sc == n3 && ia0 < c3)) { n3 = sc; c3 = ia0; }
                sc = va1 + a1.x; if (sc > n0 || (sc == n0 && ia1 < c0)) { n0 = sc; c0 = ia1; }
                sc = va1 + a1.y; if (sc > n1 || (sc == n1 && ia1 < c1)) { n1 = sc; c1 = ia1; }
                sc = va1 + a1.z; if (sc > n2 || (sc == n2 && ia1 < c2)) { n2 = sc; c2 = ia1; }
                sc = va1 + a1.w; if (sc > n3 || (sc == n3 && ia1 < c3)) { n3 = sc; c3 = ia1; }
                sc = va2 + a2.x; if (sc > n0 || (sc == n0 && ia2 < c0)) { n0 = sc; c0 = ia2; }
                sc = va2 + a2.y; if (sc > n1 || (sc == n1 && ia2 < c1)) { n1 = sc; c1 = ia2; }
                sc = va2 + a2.z; if (sc > n2 || (sc == n2 && ia2 < c2)) { n2 = sc; c2 = ia2; }
                sc = va2 + a2.w; if (sc > n3 || (sc == n3 && ia2 < c3)) { n3 = sc; c3 = ia2; }
                sc = va3 + a3.x; if (sc > n0 || (sc == n0 && ia3 < c0)) { n0 = sc; c0 = ia3; }
                sc = va3 + a3.y; if (sc > n1 || (sc == n1 && ia3 < c1)) { n1 = sc; c1 = ia3; }
                sc = va3 + a3.z; if (sc > n2 || (sc == n2 && ia3 < c2)) { n2 = sc; c2 = ia3; }
                sc = va3 + a3.w; if (sc > n3 || (sc == n3 && ia3 < c3)) { n3 = sc; c3 = ia3; }
            }
            #pragma unroll
            for (int d = 1; d <= 4; d <<= 1) {
                float mm; int bx;
                mm = __shfl_xor(n0, d, 64); bx = __shfl_xor(c0, d, 64);
                if (mm > n0 || (mm == n0 && bx < c0)) { n0 = mm; c0 = bx; }
                mm = __shfl_xor(n1, d, 64); bx = __shfl_xor(c1, d, 64);
                if (mm > n1 || (mm == n1 && bx < c1)) { n1 = mm; c1 = bx; }
                mm = __shfl_xor(n2, d, 64); bx = __shfl_xor(c2, d, 64);
                if (mm > n2 || (mm == n2 && bx < c2)) { n2 = mm; c2 = bx; }
                mm = __shfl_xor(n3, d, 64); bx = __shfl_xor(c3, d, 64);
                if (mm > n3 || (mm == n3 && bx < c3)) { n3 = mm; c3 = bx; }
            }
            if (u == 0) {
                ((float4*)lb2)[G] = make_float4(n0, n1, n2, n3);
                ((int4*)bb2)[G]   = make_int4(c0, c1, c2, c3);
            }
            __syncthreads();                 // B_D1 (rare only; uniform branch)
            if (h0) {
                float mj = lb[j];  int bj = bb[j];
                float mx = lb2[j]; int bx = bb2[j];
                if (mx > mj || (mx == mj && bx < bj)) { mj = mx; bj = bx; }
                float e  = ering[((t & 15) << 9) | j];
                float vn = mj + e;
                bp[(size_t)t * NT + j] = (unsigned short)bj;
                v = vn;
                if (t == TT - 1) vlast[j] = vn;
                float wm = vn;
                #pragma unroll
                for (int d = 1; d <= 32; d <<= 1) wm = fmaxf(wm, __shfl_xor(wm, d, 64));
                if (lane == 0) redM[wave] = wm;
            }
        }
        __syncthreads();                     // B_D
    }

    if (tid == 0)
        __hip_atomic_store(flag, 1u, __ATOMIC_RELAXED, __HIP_MEMORY_SCOPE_AGENT);
}

// ---- backtrace: per-segment map composition (verified exact) ----
__launch_bounds__(NT, 1)
__global__ void bt_maps(const unsigned short* __restrict__ bp,
                        unsigned short* __restrict__ maps) {
    __shared__ unsigned short bps[BT_L * NT];
    const int s = blockIdx.x;
    const int tlo = BT_L * s + 1;
    int thi = BT_L * (s + 1); if (thi > TT - 1) thi = TT - 1;
    const int nt = thi - tlo + 1;
    for (int k = threadIdx.x; k < nt * NT; k += NT)
        bps[k] = bp[(size_t)tlo * NT + k];
    __syncthreads();
    int cur = threadIdx.x;
    for (int r = nt - 1; r >= 0; --r) cur = bps[r * NT + cur];
    maps[s * NT + threadIdx.x] = (unsigned short)cur;
}

__launch_bounds__(NT, 1)
__global__ void bt_bound(const float* __restrict__ vlast,
                         const unsigned short* __restrict__ maps,
                         int* __restrict__ bound) {
    __shared__ float sv[NT];
    __shared__ int   si[NT];
    int j = threadIdx.x;
    sv[j] = vlast[j]; si[j] = j;
    __syncthreads();
    for (int off = NT / 2; off > 0; off >>= 1) {
        if (j < off) {
            float v2 = sv[j + off]; int i2 = si[j + off];
            if (v2 > sv[j] || (v2 == sv[j] && i2 < si[j])) { sv[j] = v2; si[j] = i2; }
        }
        __syncthreads();
    }
    if (j == 0) {
        int cur = si[0];
        bound[BT_S] = cur;
        for (int s = BT_S - 1; s >= 0; --s) {
            cur = maps[s * NT + cur];
            bound[s] = cur;
        }
    }
}

__launch_bounds__(NT, 1)
__global__ void bt_path(const unsigned short* __restrict__ bp,
                        const int* __restrict__ bound,
                        int* __restrict__ path) {
    __shared__ unsigned short bps[BT_L * NT];
    const int s = blockIdx.x;
    const int tlo = BT_L * s + 1;
    int thi = BT_L * (s + 1); if (thi > TT - 1) thi = TT - 1;
    const int nt = thi - tlo + 1;
    for (int k = threadIdx.x; k < nt * NT; k += NT)
        bps[k] = bp[(size_t)tlo * NT + k];
    __syncthreads();
    if (threadIdx.x == 0) {
        int cur = bound[s + 1];
        if (s == BT_S - 1) path[TT - 1] = cur;
        for (int r = nt - 1; r >= 0; --r) {
            cur = bps[r * NT + cur];
            path[tlo - 1 + r] = cur;
        }
    }
}

extern "C" void kernel_launch(void* const* d_in, const int* in_sizes, int n_in,
                              void* d_out, int out_size, void* d_ws, size_t ws_size,
                              hipStream_t stream) {
    const int*   tok = (const int*)d_in[0];
    const float* A   = (const float*)d_in[1];
    const float* B   = (const float*)d_in[2];
    const float* Pi  = (const float*)d_in[3];
    int* path = (int*)d_out;
    char* ws = (char*)d_ws;
    if (ws_size < (size_t)WS_NEED) return;

    float* logPi          = (float*)(ws + WS_LOGPI);
    float* vlast          = (float*)(ws + WS_VLAST);
    int*   bound          = (int*)(ws + WS_BOUND);
    unsigned int* flag    = (unsigned int*)(ws + WS_FLAG);
    float* rowmax         = (float*)(ws + WS_ROWMAX);
    unsigned short* maps  = (unsigned short*)(ws + WS_MAPS);
    float* lA             = (float*)(ws + WS_LA);
    float* emis           = (float*)(ws + WS_EMIS);
    unsigned short* bpp   = (unsigned short*)(ws + WS_BP);

    prep_logs  <<<(NT * NT + NT + 256) / 256, 256, 0, stream>>>(A, Pi, lA, logPi, flag);
    prep_emis  <<<(TT * NT) / 256,            256, 0, stream>>>(B, tok, emis);
    prep_rowmax<<<NT, 256, 0, stream>>>(lA, rowmax);
    viterbi_fwd_exact<<<256, 1024, 0, stream>>>(lA, rowmax, emis, logPi, bpp, vlast, flag);
    bt_maps  <<<BT_S, NT, 0, stream>>>(bpp, maps);
    bt_bound <<<1,    NT, 0, stream>>>(vlast, maps, bound);
    bt_path  <<<BT_S, NT, 0, stream>>>(bpp, bound, path);
}